// Round 9
// baseline (41.985 us; speedup 1.0000x reference)
//
#include <hip/hip_runtime.h>
#include <math.h>

#define Ee 100
#define Hh 64
#define Bb 64
#define Tt 20
#define Kk 50
#define NROWS 16128
#define NQUADS 4032
#define BBLKS 64
#define QBLKS 448
#define NBLK (BBLKS + QBLKS)

// LDS float offsets (basket role). P aliases rcT after the tile phase.
#define O_ACT   0       // [100][52]  acT[e*52+k] = alpha[itemset[k]][e]
#define O_RCT   5200    // [100][52]
#define O_P     5200    // [50][51]  (aliases rcT)
#define O_ALS   10400   // [50][51]  A[k][j]
#define O_RDA   12950   // [20][50]  rda0[t][j]
#define O_RA0   13950   // [20][50]  ra0c[t][k]
#define O_KESC  14950   // [50]
#define O_KES0  15000   // [20]
#define O_SELF  15020   // [20]
#define O_TH    15040   // [100]
#define O_GA    15140   // [100]
#define O_IIS   15240   // 50 ints
#define O_IID   15292   // 20 ints
#define O_RED   15312   // 8
#define LDSF    15320   // 61280 B -> exactly 2 blocks/CU

__device__ __forceinline__ float wave_sum(float v) {
    #pragma unroll
    for (int m = 32; m >= 1; m >>= 1) v += __shfl_xor(v, m, 64);
    return v;
}
__device__ __forceinline__ float rl(float v, int l) {
    return __uint_as_float(__builtin_amdgcn_readlane(__float_as_uint(v), l));
}

__global__ __launch_bounds__(256) void k_fused(
    const float* __restrict__ alpha, const float* __restrict__ rho,
    const float* __restrict__ lam,   const float* __restrict__ beta,
    const float* __restrict__ mu_tab,const float* __restrict__ theta,
    const float* __restrict__ gamma_,const float* __restrict__ w1,
    const float* __restrict__ b1,    const float* __restrict__ w2,
    const float* __restrict__ b2,    const float* __restrict__ sigma_list,
    const float* __restrict__ prices,const float* __restrict__ price_table,
    const int* __restrict__ item_ids,const int* __restrict__ itemset,
    const int* __restrict__ userid,
    float* __restrict__ partial)
{
    __shared__ float buf[LDSF];
    const int tid  = threadIdx.x;
    const int lane = tid & 63;
    const int wid  = tid >> 6;

    if (blockIdx.x < BBLKS) {
        // ======================= basket role: one block per b =======================
        const int b = blockIdx.x;
        int* iis = (int*)&buf[O_IIS];
        int* iid = (int*)&buf[O_IID];

        if (tid < Kk) iis[tid] = itemset[b*Kk + tid];
        else if (tid < Kk + Tt) iid[tid - Kk] = item_ids[b*Tt + (tid - Kk)];
        {
            const long uid = userid[b];
            if (tid >= 64 && tid < 89)
                *(float4*)&buf[O_TH + 4*(tid-64)] = *(const float4*)&theta[uid*Ee + 4*(tid-64)];
            else if (tid >= 96 && tid < 121)
                *(float4*)&buf[O_GA + 4*(tid-96)] = *(const float4*)&gamma_[uid*Ee + 4*(tid-96)];
        }
        for (int i = tid; i < 2500; i += 256) {
            int half = (i < 1250) ? 0 : 1;
            int ii = i - half*1250;
            int k = ii % Kk, c = ii / Kk;
            long idx = itemset[b*Kk + k];
            float4 v = *(const float4*)((half ? rho : alpha) + idx*Ee + 4*c);
            float* dst = &buf[half ? O_RCT : O_ACT];
            dst[(4*c+0)*52+k] = v.x; dst[(4*c+1)*52+k] = v.y;
            dst[(4*c+2)*52+k] = v.z; dst[(4*c+3)*52+k] = v.w;
        }
        __syncthreads();

        // ---- tile phase: A (169), rda/ra0c (130), kesc (50), kes0 (20) ----
        for (int task = tid; task < 369; task += 256) {
            if (task < 169) {
                int kt = task / 13, jt = task - 13*(task/13);
                int k0 = 4*kt, j0 = 4*jt;
                float acc[4][4] = {};
                #pragma unroll 4
                for (int e = 0; e < Ee; ++e) {
                    float4 a4 = *(const float4*)&buf[O_ACT + e*52 + k0];
                    float4 r4 = *(const float4*)&buf[O_RCT + e*52 + j0];
                    acc[0][0]=fmaf(a4.x,r4.x,acc[0][0]); acc[0][1]=fmaf(a4.x,r4.y,acc[0][1]);
                    acc[0][2]=fmaf(a4.x,r4.z,acc[0][2]); acc[0][3]=fmaf(a4.x,r4.w,acc[0][3]);
                    acc[1][0]=fmaf(a4.y,r4.x,acc[1][0]); acc[1][1]=fmaf(a4.y,r4.y,acc[1][1]);
                    acc[1][2]=fmaf(a4.y,r4.z,acc[1][2]); acc[1][3]=fmaf(a4.y,r4.w,acc[1][3]);
                    acc[2][0]=fmaf(a4.z,r4.x,acc[2][0]); acc[2][1]=fmaf(a4.z,r4.y,acc[2][1]);
                    acc[2][2]=fmaf(a4.z,r4.z,acc[2][2]); acc[2][3]=fmaf(a4.z,r4.w,acc[2][3]);
                    acc[3][0]=fmaf(a4.w,r4.x,acc[3][0]); acc[3][1]=fmaf(a4.w,r4.y,acc[3][1]);
                    acc[3][2]=fmaf(a4.w,r4.z,acc[3][2]); acc[3][3]=fmaf(a4.w,r4.w,acc[3][3]);
                }
                int km = Kk - k0; if (km > 4) km = 4;
                int jm = Kk - j0; if (jm > 4) jm = 4;
                #pragma unroll
                for (int a = 0; a < 4; ++a)
                    #pragma unroll
                    for (int c2 = 0; c2 < 4; ++c2)
                        if (a < km && c2 < jm)
                            buf[O_ALS + (k0+a)*51 + (j0+c2)] = acc[a][c2];
            } else if (task < 299) {
                int t2 = task - 169;
                int tt = t2 / 13, jt = t2 - 13*tt;
                int t0 = 2*tt, j0 = 4*jt;
                long ia0 = iid[t0], ia1 = iid[t0+1];
                const float *a0p0 = alpha + ia0*Ee, *r0p0 = rho + ia0*Ee;
                const float *a0p1 = alpha + ia1*Ee, *r0p1 = rho + ia1*Ee;
                float p0[4]={},p1[4]={},q0[4]={},q1[4]={};
                for (int c = 0; c < 25; ++c) {
                    float4 av0 = *(const float4*)(a0p0 + 4*c);
                    float4 av1 = *(const float4*)(a0p1 + 4*c);
                    float4 rv0 = *(const float4*)(r0p0 + 4*c);
                    float4 rv1 = *(const float4*)(r0p1 + 4*c);
                    #define RDA_STEP(d, comp)                                               \
                    {   float4 rc4 = *(const float4*)&buf[O_RCT + (4*c+d)*52 + j0];         \
                        float4 ac4 = *(const float4*)&buf[O_ACT + (4*c+d)*52 + j0];         \
                        p0[0]=fmaf(rc4.x,av0.comp,p0[0]); p0[1]=fmaf(rc4.y,av0.comp,p0[1]); \
                        p0[2]=fmaf(rc4.z,av0.comp,p0[2]); p0[3]=fmaf(rc4.w,av0.comp,p0[3]); \
                        p1[0]=fmaf(rc4.x,av1.comp,p1[0]); p1[1]=fmaf(rc4.y,av1.comp,p1[1]); \
                        p1[2]=fmaf(rc4.z,av1.comp,p1[2]); p1[3]=fmaf(rc4.w,av1.comp,p1[3]); \
                        q0[0]=fmaf(rv0.comp,ac4.x,q0[0]); q0[1]=fmaf(rv0.comp,ac4.y,q0[1]); \
                        q0[2]=fmaf(rv0.comp,ac4.z,q0[2]); q0[3]=fmaf(rv0.comp,ac4.w,q0[3]); \
                        q1[0]=fmaf(rv1.comp,ac4.x,q1[0]); q1[1]=fmaf(rv1.comp,ac4.y,q1[1]); \
                        q1[2]=fmaf(rv1.comp,ac4.z,q1[2]); q1[3]=fmaf(rv1.comp,ac4.w,q1[3]); }
                    RDA_STEP(0,x) RDA_STEP(1,y) RDA_STEP(2,z) RDA_STEP(3,w)
                    #undef RDA_STEP
                }
                int jm = Kk - j0; if (jm > 4) jm = 4;
                #pragma unroll
                for (int jj = 0; jj < 4; ++jj) if (jj < jm) {
                    buf[O_RDA + t0*50 + j0+jj] = p0[jj];
                    buf[O_RDA + (t0+1)*50 + j0+jj] = p1[jj];
                    buf[O_RA0 + t0*50 + j0+jj] = q0[jj];
                    buf[O_RA0 + (t0+1)*50 + j0+jj] = q1[jj];
                }
            } else if (task < 349) {
                int k = task - 299;
                long idx = iis[k];
                const float *lp = lam + idx*Ee, *bp = beta + idx*Ee;
                float ml=0.f, mtha=0.f, mgb=0.f;
                for (int c = 0; c < 25; ++c) {
                    float4 l4 = *(const float4*)(lp + 4*c);
                    float4 b4 = *(const float4*)(bp + 4*c);
                    float4 t4 = *(const float4*)&buf[O_TH + 4*c];
                    float4 g4 = *(const float4*)&buf[O_GA + 4*c];
                    ml  += (l4.x + l4.y) + (l4.z + l4.w);
                    mgb += g4.x*b4.x + g4.y*b4.y + g4.z*b4.z + g4.w*b4.w;
                    float a0 = buf[O_ACT + (4*c+0)*52 + k];
                    float a1 = buf[O_ACT + (4*c+1)*52 + k];
                    float a2 = buf[O_ACT + (4*c+2)*52 + k];
                    float a3 = buf[O_ACT + (4*c+3)*52 + k];
                    mtha += t4.x*a0 + t4.y*a1 + t4.z*a2 + t4.w*a3;
                }
                buf[O_KESC + k] = 0.01f*(ml + mtha) - 0.01f*mgb*logf(price_table[idx]);
            } else {
                int t = task - 349;
                long ia = iid[t];
                const float *ap = alpha + ia*Ee, *rp = rho + ia*Ee;
                const float *lp = lam + ia*Ee,  *bp = beta + ia*Ee;
                float self=0.f, ml=0.f, mtha=0.f, mgb=0.f;
                for (int c = 0; c < 25; ++c) {
                    float4 a4 = *(const float4*)(ap + 4*c);
                    float4 r4 = *(const float4*)(rp + 4*c);
                    float4 l4 = *(const float4*)(lp + 4*c);
                    float4 b4 = *(const float4*)(bp + 4*c);
                    float4 t4 = *(const float4*)&buf[O_TH + 4*c];
                    float4 g4 = *(const float4*)&buf[O_GA + 4*c];
                    self += a4.x*r4.x + a4.y*r4.y + a4.z*r4.z + a4.w*r4.w;
                    ml   += (l4.x + l4.y) + (l4.z + l4.w);
                    mtha += t4.x*a4.x + t4.y*a4.y + t4.z*a4.z + t4.w*a4.w;
                    mgb  += g4.x*b4.x + g4.y*b4.y + g4.z*b4.z + g4.w*b4.w;
                }
                buf[O_SELF + t] = self;
                buf[O_KES0 + t] = 0.01f*(ml + mtha) - 0.01f*mgb*logf(prices[b*Tt + t]);
            }
        }
        __syncthreads();

        // ---- P build (unmasked prefix over k), wave 0 ----
        if (wid == 0 && lane < Kk) {
            float s = 0.f;
            #pragma unroll 5
            for (int k = 0; k < Kk; ++k) {
                s += buf[O_ALS + k*51 + lane];
                buf[O_P + k*51 + lane] = s;
            }
        }
        __syncthreads();

        // ---- main: wave handles t = 5*wid..5*wid+4; lane = k. All LDS, no reg arrays. ----
        const int lc = (lane < Kk) ? lane : 0;
        float bacc = 0.f;
        for (int it = 0; it < 5; ++it) {
            const int t = wid*5 + it;
            const int item = iid[t];
            bool eq = (lane < Kk) && (iis[lane] == item);
            unsigned long long mq = __ballot(eq);
            int p_t = mq ? (int)__ffsll((long long)mq) - 1 : -1;
            const int pr = (p_t < 0) ? 0 : p_t;

            float raj    = (lane < Kk) ? buf[O_RA0 + t*50 + lane] : 0.f;
            float rj_own = (lane < Kk) ? buf[O_RDA + t*50 + lane] : 0.f;
            float pv = raj;
            #pragma unroll
            for (int off = 1; off <= 32; off <<= 1) {
                float u = __shfl_up(pv, off, 64);
                if (lane >= off) pv += u;
            }
            float rasub = (p_t >= 0) ? rl(raj, p_t) : 0.f;
            float cumra = pv - ((p_t >= 0 && lane >= p_t) ? rasub : 0.f);

            int sub_le = (p_t >= 0 && p_t <= lane) ? 1 : 0;
            float len    = (float)(lane + 2 - sub_le);
            float invden = 1.f / ((len + 1.f) * 100.f);
            float invlen = 1.f / (100.f * len);
            float subf   = (p_t >= 0 && lane >= p_t) ? 1.f : 0.f;

            float max0 = -3e38f, maxc = -3e38f, diag = 0.f;
            #pragma unroll 5
            for (int j = 0; j < Kk; ++j) {
                float Pj  = buf[O_P   + lc*51 + j];   // column, stride 51 -> conflict-free
                float Aj  = buf[O_ALS + lc*51 + j];   // column
                float Apt = buf[O_ALS + pr*51 + j];   // broadcast
                float rjj = buf[O_RDA + t*50 + j];    // broadcast
                float kcj = buf[O_KESC + j];          // broadcast
                float Cum = fmaf(-subf, Apt, Pj);
                float v0 = fmaf(fmaf(2.f, rjj, Cum), invden, kcj);
                float vc = fmaf(Cum + rjj + Aj,      invden, kcj);
                bool elig = (j > lane) && (j != p_t);
                max0 = elig ? fmaxf(max0, v0) : max0;
                maxc = elig ? fmaxf(maxc, vc) : maxc;
                if (j == lane) diag = Cum;
            }
            float Kes0 = buf[O_KES0 + t]
                       + fmaf(buf[O_SELF + t] + cumra, invlen, fmaxf(0.f, max0));
            float KesC = buf[O_KESC + lc]
                       + fmaf(rj_own + diag, invlen, fmaxf(0.f, maxc));
            float x = Kes0 - KesC;
            float term = (x >= 0.f) ? -log1pf(expf(-x)) : (x - log1pf(expf(x)));
            if (lane < Kk && lane != p_t) bacc += term;
        }
        float s = wave_sum(bacc);
        if (lane == 0) buf[O_RED + wid] = s;
        __syncthreads();
        if (tid == 0)
            partial[b] = buf[O_RED] + buf[O_RED+1] + buf[O_RED+2] + buf[O_RED+3];
    } else {
        // ======================= qprior role (quads + readlane) =======================
        float* w1s = buf;          // [64][100] row-major
        float* red = buf + 6400;

        for (int i = tid; i < Hh*Ee/4; i += 256)
            *(float4*)&w1s[4*i] = *(const float4*)&w1[4*i];
        __syncthreads();

        const float w2j = w2[lane];
        const float b1j = b1[lane];
        const float b2v = b2[0];
        const float c0 = -0.5f/sigma_list[0], c1 = -0.5f/sigma_list[1];
        const float c2 = -0.5f/sigma_list[2], c3 = -0.5f/sigma_list[3];
        const float c4 = -0.5f/sigma_list[4], c5 = -0.5f/sigma_list[5];
        const float c6 = -0.5f/sigma_list[6];

        const bool ldA = (lane < 25);
        const bool ldB = (lane >= 32) && (lane < 57);
        const int  lq  = ldA ? (lane<<2) : ((lane-32)<<2);
        const int  wave = (blockIdx.x - BBLKS)*4 + wid;   // 0..1791

        #define LOAD_QUAD(Q, AB, CD, CF)                                          \
        {                                                                         \
            int r4_ = 4*(Q);                                                      \
            const float* tab_; int4 ii_;                                          \
            if (r4_ < 16000) {                                                    \
                int seg_ = r4_/3200;                                              \
                ii_ = *(const int4*)&itemset[r4_ - seg_*3200];                    \
                tab_ = (seg_==0)?alpha:(seg_==1)?rho:(seg_==2)?lam                \
                      :(seg_==3)?beta:mu_tab;                                     \
                CF = (seg_==0)?c0:(seg_==1)?c1:(seg_==2)?c2:(seg_==3)?c3:c4;      \
            } else if (r4_ < 16064) {                                             \
                ii_ = *(const int4*)&userid[r4_-16000]; tab_ = theta;  CF = c5;   \
            } else {                                                              \
                ii_ = *(const int4*)&userid[r4_-16064]; tab_ = gamma_; CF = c6;   \
            }                                                                     \
            if (ldA) {                                                            \
                AB = *(const float4*)(tab_ + (long)ii_.x*Ee + lq);                \
                CD = *(const float4*)(tab_ + (long)ii_.z*Ee + lq);                \
            } else if (ldB) {                                                     \
                AB = *(const float4*)(tab_ + (long)ii_.y*Ee + lq);                \
                CD = *(const float4*)(tab_ + (long)ii_.w*Ee + lq);                \
            }                                                                     \
        }

        float ssacc = 0.f, qacc = 0.f;
        float4 curAB = make_float4(0.f,0.f,0.f,0.f);
        float4 curCD = make_float4(0.f,0.f,0.f,0.f);
        float  ccur = 0.f;
        int qd = wave;
        if (qd < NQUADS) LOAD_QUAD(qd, curAB, curCD, ccur);

        while (qd < NQUADS) {
            float4 nAB = make_float4(0.f,0.f,0.f,0.f);
            float4 nCD = make_float4(0.f,0.f,0.f,0.f);
            float  cnx = 0.f;
            int qn = qd + QBLKS*4;
            if (qn < NQUADS) LOAD_QUAD(qn, nAB, nCD, cnx);

            if (ldA || ldB)
                ssacc += ccur * (curAB.x*curAB.x + curAB.y*curAB.y
                               + curAB.z*curAB.z + curAB.w*curAB.w
                               + curCD.x*curCD.x + curCD.y*curCD.y
                               + curCD.z*curCD.z + curCD.w*curCD.w);

            float hA0=b1j, hA1=0.f, hB0=b1j, hB1=0.f;
            float hC0=b1j, hC1=0.f, hD0=b1j, hD1=0.f;
            #pragma unroll
            for (int i = 0; i < 25; ++i) {
                float4 wv = *(const float4*)&w1s[lane*Ee + 4*i];
                hA0 = fmaf(rl(curAB.x, i),    wv.x, hA0);
                hA1 = fmaf(rl(curAB.y, i),    wv.y, hA1);
                hA0 = fmaf(rl(curAB.z, i),    wv.z, hA0);
                hA1 = fmaf(rl(curAB.w, i),    wv.w, hA1);
                hB0 = fmaf(rl(curAB.x, 32+i), wv.x, hB0);
                hB1 = fmaf(rl(curAB.y, 32+i), wv.y, hB1);
                hB0 = fmaf(rl(curAB.z, 32+i), wv.z, hB0);
                hB1 = fmaf(rl(curAB.w, 32+i), wv.w, hB1);
                hC0 = fmaf(rl(curCD.x, i),    wv.x, hC0);
                hC1 = fmaf(rl(curCD.y, i),    wv.y, hC1);
                hC0 = fmaf(rl(curCD.z, i),    wv.z, hC0);
                hC1 = fmaf(rl(curCD.w, i),    wv.w, hC1);
                hD0 = fmaf(rl(curCD.x, 32+i), wv.x, hD0);
                hD1 = fmaf(rl(curCD.y, 32+i), wv.y, hD1);
                hD0 = fmaf(rl(curCD.z, 32+i), wv.z, hD0);
                hD1 = fmaf(rl(curCD.w, 32+i), wv.w, hD1);
            }
            float vA = fmaxf(hA0+hA1, 0.f)*w2j;
            float vB = fmaxf(hB0+hB1, 0.f)*w2j;
            float vC = fmaxf(hC0+hC1, 0.f)*w2j;
            float vD = fmaxf(hD0+hD1, 0.f)*w2j;
            #pragma unroll
            for (int m = 32; m >= 1; m >>= 1) {
                vA += __shfl_xor(vA, m, 64);
                vB += __shfl_xor(vB, m, 64);
                vC += __shfl_xor(vC, m, 64);
                vD += __shfl_xor(vD, m, 64);
            }
            qacc -= 1.f/(1.f+expf(-(vA+b2v))) + 1.f/(1.f+expf(-(vB+b2v)))
                  + 1.f/(1.f+expf(-(vC+b2v))) + 1.f/(1.f+expf(-(vD+b2v)));

            curAB = nAB; curCD = nCD; ccur = cnx; qd = qn;
        }
        #undef LOAD_QUAD

        float s = wave_sum(ssacc);
        if (lane == 0) red[wid] = s + qacc;
        __syncthreads();
        if (tid == 0)
            partial[blockIdx.x] = red[0]+red[1]+red[2]+red[3];
    }
}

// ---------- kernel 2: deterministic final reduce ----------
__global__ __launch_bounds__(256) void k_final(
    const float* __restrict__ p, int n, float* __restrict__ out)
{
    __shared__ double sh[256];
    double s = 0.0;
    for (int i = threadIdx.x; i < n; i += 256) s += (double)p[i];
    sh[threadIdx.x] = s;
    __syncthreads();
    for (int m = 128; m >= 1; m >>= 1) {
        if (threadIdx.x < m) sh[threadIdx.x] += sh[threadIdx.x + m];
        __syncthreads();
    }
    if (threadIdx.x == 0) out[0] = (float)sh[0];
}

// ---------- launch ----------
extern "C" void kernel_launch(void* const* d_in, const int* in_sizes, int n_in,
                              void* d_out, int out_size, void* d_ws, size_t ws_size,
                              hipStream_t stream) {
    const float* alpha      = (const float*)d_in[0];
    const float* rho        = (const float*)d_in[1];
    const float* lam        = (const float*)d_in[2];
    const float* beta       = (const float*)d_in[3];
    const float* mu_tab     = (const float*)d_in[4];
    const float* theta      = (const float*)d_in[5];
    const float* gamma_     = (const float*)d_in[6];
    const float* w1         = (const float*)d_in[7];
    const float* b1         = (const float*)d_in[8];
    const float* w2         = (const float*)d_in[9];
    const float* b2         = (const float*)d_in[10];
    const float* sigma_list = (const float*)d_in[11];
    // d_in[12] = mu_list (zeros; folded out)
    const float* prices      = (const float*)d_in[13];
    const float* price_table = (const float*)d_in[14];
    const int*   item_ids    = (const int*)d_in[15];
    const int*   itemset     = (const int*)d_in[16];
    const int*   userid      = (const int*)d_in[17];

    float* ws = (float*)d_ws;   // partial[NBLK]

    k_fused<<<NBLK, 256, 0, stream>>>(
        alpha, rho, lam, beta, mu_tab, theta, gamma_,
        w1, b1, w2, b2, sigma_list, prices, price_table,
        item_ids, itemset, userid, ws);
    k_final<<<1, 256, 0, stream>>>(ws, NBLK, (float*)d_out);
}

// Round 10
// 36.364 us; speedup vs baseline: 1.1546x; 1.1546x over previous
//
#include <hip/hip_runtime.h>
#include <math.h>

#define Ee 100
#define Hh 64
#define Bb 64
#define Tt 20
#define Kk 50
#define NROWS 16128
#define NQUADS 4032
#define PREBLKS 256
#define QBLKS   512
#define NB3 (Bb*Tt)              // 1280

// ---------- helpers ----------
__device__ __forceinline__ float wave_sum(float v) {
    #pragma unroll
    for (int m = 32; m >= 1; m >>= 1) v += __shfl_xor(v, m, 64);
    return v;
}
__device__ __forceinline__ float rl(float v, int l) {
    return __uint_as_float(__builtin_amdgcn_readlane(__float_as_uint(v), l));
}

// ---------- kernel A: fused {per-b precompute (4 blocks/b, transposed tiles)} + {qprior} ----------
__global__ __launch_bounds__(256) void k_fused1(
    const float* __restrict__ alpha, const float* __restrict__ rho,
    const float* __restrict__ lam,   const float* __restrict__ beta,
    const float* __restrict__ mu_tab,const float* __restrict__ theta,
    const float* __restrict__ gamma_,const float* __restrict__ w1,
    const float* __restrict__ b1,    const float* __restrict__ w2,
    const float* __restrict__ b2,    const float* __restrict__ sigma_list,
    const float* __restrict__ prices,const float* __restrict__ price_table,
    const int* __restrict__ item_ids,const int* __restrict__ itemset,
    const int* __restrict__ userid,
    float* __restrict__ A, float* __restrict__ rda0, float* __restrict__ ra0c,
    float* __restrict__ kesc, float* __restrict__ kes0, float* __restrict__ rda0self,
    float* __restrict__ partialQ)
{
    __shared__ float buf[12260];
    const int tid  = threadIdx.x;
    const int lane = tid & 63;
    const int wid  = tid >> 6;

    if (blockIdx.x < PREBLKS) {
        // ================= pre role (4 blocks per b), transposed float4 tiles =================
        float* acT = buf;            // [100][52]  acT[e*52+k]
        float* rcT = buf + 5200;     // [100][52]
        float* a0T = buf + 10400;    // [100][8]   a0T[e*8+tl]
        float* r0T = buf + 11200;    // [100][8]
        float* th  = buf + 12000;    // 100
        float* ga  = buf + 12100;    // 100
        int*   iis = (int*)&buf[12200];  // 50
        int*   iid5= (int*)&buf[12252];  // 5

        const int b = blockIdx.x >> 2, q = blockIdx.x & 3;
        const int kcnt = (q < 2) ? 13 : 12;
        const int kbeg = q*12 + ((q < 2) ? q : 2);
        const int tbeg = q*5;
        const long uid = userid[b];

        // stage indices + th/ga
        if (tid < Kk) iis[tid] = itemset[b*Kk + tid];
        else if (tid >= 56 && tid < 61) iid5[tid-56] = item_ids[b*Tt + tbeg + (tid-56)];
        for (int i = tid; i < Ee; i += 256) {
            th[i] = theta[uid*Ee+i];
            ga[i] = gamma_[uid*Ee+i];
        }
        __syncthreads();

        // transposed staging: ac/rc (50 rows), a0/r0 (5 rows)
        for (int i = tid; i < 2500; i += 256) {
            int half = (i < 1250) ? 0 : 1;
            int ii = i - half*1250;
            int k = ii % Kk, c = ii / Kk;
            long idx = iis[k];
            float4 v = *(const float4*)((half ? rho : alpha) + idx*Ee + 4*c);
            float* dst = half ? rcT : acT;
            dst[(4*c+0)*52+k] = v.x; dst[(4*c+1)*52+k] = v.y;
            dst[(4*c+2)*52+k] = v.z; dst[(4*c+3)*52+k] = v.w;
        }
        for (int i = tid; i < 250; i += 256) {
            int half = (i < 125) ? 0 : 1;
            int ii = i - half*125;
            int tl = ii % 5, c = ii / 5;
            long idx = iid5[tl];
            float4 v = *(const float4*)((half ? rho : alpha) + idx*Ee + 4*c);
            float* dst = half ? r0T : a0T;
            dst[(4*c+0)*8+tl] = v.x; dst[(4*c+1)*8+tl] = v.y;
            dst[(4*c+2)*8+tl] = v.z; dst[(4*c+3)*8+tl] = v.w;
        }
        __syncthreads();

        if (tid < kcnt*13) {
            // A tile: 1 k x 4 j
            int k = kbeg + tid/13, jt = tid - (tid/13)*13, j0 = 4*jt;
            float s0=0.f, s1=0.f, s2=0.f, s3=0.f;
            #pragma unroll 4
            for (int e = 0; e < Ee; ++e) {
                float a  = acT[e*52 + k];
                float4 r = *(const float4*)&rcT[e*52 + j0];
                s0 = fmaf(a, r.x, s0); s1 = fmaf(a, r.y, s1);
                s2 = fmaf(a, r.z, s2); s3 = fmaf(a, r.w, s3);
            }
            float* dst = A + ((long)b*Kk + k)*Kk + j0;
            dst[0] = s0; dst[1] = s1;
            if (jt < 12) { dst[2] = s2; dst[3] = s3; }
        } else if (tid < kcnt*13 + 65) {
            // rda0/ra0c tile: 1 t x 4 j
            int t2 = tid - kcnt*13;
            int tl = t2/13, jt = t2 - 13*tl, j0 = 4*jt;
            float p0=0.f,p1=0.f,p2=0.f,p3=0.f, q0=0.f,q1=0.f,q2=0.f,q3=0.f;
            #pragma unroll 4
            for (int e = 0; e < Ee; ++e) {
                float a0v = a0T[e*8 + tl];
                float r0v = r0T[e*8 + tl];
                float4 r = *(const float4*)&rcT[e*52 + j0];
                float4 a = *(const float4*)&acT[e*52 + j0];
                p0 = fmaf(r.x, a0v, p0); p1 = fmaf(r.y, a0v, p1);
                p2 = fmaf(r.z, a0v, p2); p3 = fmaf(r.w, a0v, p3);
                q0 = fmaf(r0v, a.x, q0); q1 = fmaf(r0v, a.y, q1);
                q2 = fmaf(r0v, a.z, q2); q3 = fmaf(r0v, a.w, q3);
            }
            int t = tbeg + tl;
            float* d1 = rda0 + ((long)b*Tt + t)*Kk + j0;
            float* d2 = ra0c + ((long)b*Tt + t)*Kk + j0;
            d1[0]=p0; d1[1]=p1; d2[0]=q0; d2[1]=q1;
            if (jt < 12) { d1[2]=p2; d1[3]=p3; d2[2]=q2; d2[3]=q3; }
        }

        // tails (wave-parallel over e)
        for (int task = wid; task < 5 + kcnt; task += 4) {
            if (task < 5) {
                int tl = task, t = tbeg + tl;
                long idx = iid5[tl];
                float s=0.f, ml=0.f, mtha=0.f, mgb=0.f;
                if (lane < Kk) {
                    #pragma unroll
                    for (int u = 0; u < 2; ++u) {
                        int e = lane + u*Kk;
                        float a0v = a0T[e*8+tl], r0v = r0T[e*8+tl];
                        s    = fmaf(r0v, a0v, s);
                        ml  += lam[idx*Ee+e];
                        mtha = fmaf(th[e], a0v, mtha);
                        mgb  = fmaf(ga[e], beta[idx*Ee+e], mgb);
                    }
                }
                s = wave_sum(s); ml = wave_sum(ml); mtha = wave_sum(mtha); mgb = wave_sum(mgb);
                if (lane == 0) {
                    rda0self[b*Tt+t] = s;
                    kes0[b*Tt+t] = 0.01f*ml + 0.01f*mtha - 0.01f*mgb*logf(prices[b*Tt+t]);
                }
            } else {
                int k = kbeg + (task - 5);
                long idx = iis[k];
                float ml=0.f, mtha=0.f, mgb=0.f;
                if (lane < Kk) {
                    #pragma unroll
                    for (int u = 0; u < 2; ++u) {
                        int e = lane + u*Kk;
                        ml  += lam[idx*Ee+e];
                        mtha = fmaf(th[e], acT[e*52+k], mtha);
                        mgb  = fmaf(ga[e], beta[idx*Ee+e], mgb);
                    }
                }
                ml = wave_sum(ml); mtha = wave_sum(mtha); mgb = wave_sum(mgb);
                if (lane == 0)
                    kesc[b*Kk+k] = 0.01f*ml + 0.01f*mtha - 0.01f*mgb*logf(price_table[idx]);
            }
        }
    } else {
        // ================= qprior role: quads + readlane broadcasts =================
        float* w1s = buf;          // [64][100] row-major; b128 own-row reads
        float* red = buf + 6400;

        for (int i = tid; i < Hh*Ee/4; i += 256)
            *(float4*)&w1s[4*i] = *(const float4*)&w1[4*i];
        __syncthreads();

        const float w2j = w2[lane];
        const float b1j = b1[lane];
        const float b2v = b2[0];
        const float c0 = -0.5f/sigma_list[0], c1 = -0.5f/sigma_list[1];
        const float c2 = -0.5f/sigma_list[2], c3 = -0.5f/sigma_list[3];
        const float c4 = -0.5f/sigma_list[4], c5 = -0.5f/sigma_list[5];
        const float c6 = -0.5f/sigma_list[6];

        const bool ldA = (lane < 25);
        const bool ldB = (lane >= 32) && (lane < 57);
        const int  lq  = ldA ? (lane<<2) : ((lane-32)<<2);
        const int  wave = (blockIdx.x - PREBLKS)*4 + wid;   // 0..2047

        #define LOAD_QUAD(Q, AB, CD, CF)                                          \
        {                                                                         \
            int r4_ = 4*(Q);                                                      \
            const float* tab_; int4 ii_;                                          \
            if (r4_ < 16000) {                                                    \
                int seg_ = r4_/3200;                                              \
                ii_ = *(const int4*)&itemset[r4_ - seg_*3200];                    \
                tab_ = (seg_==0)?alpha:(seg_==1)?rho:(seg_==2)?lam                \
                      :(seg_==3)?beta:mu_tab;                                     \
                CF = (seg_==0)?c0:(seg_==1)?c1:(seg_==2)?c2:(seg_==3)?c3:c4;      \
            } else if (r4_ < 16064) {                                             \
                ii_ = *(const int4*)&userid[r4_-16000]; tab_ = theta;  CF = c5;   \
            } else {                                                              \
                ii_ = *(const int4*)&userid[r4_-16064]; tab_ = gamma_; CF = c6;   \
            }                                                                     \
            if (ldA) {                                                            \
                AB = *(const float4*)(tab_ + (long)ii_.x*Ee + lq);                \
                CD = *(const float4*)(tab_ + (long)ii_.z*Ee + lq);                \
            } else if (ldB) {                                                     \
                AB = *(const float4*)(tab_ + (long)ii_.y*Ee + lq);                \
                CD = *(const float4*)(tab_ + (long)ii_.w*Ee + lq);                \
            }                                                                     \
        }

        float ssacc = 0.f, qacc = 0.f;
        float4 curAB = make_float4(0.f,0.f,0.f,0.f);
        float4 curCD = make_float4(0.f,0.f,0.f,0.f);
        float  ccur = 0.f;
        int qd = wave;
        if (qd < NQUADS) LOAD_QUAD(qd, curAB, curCD, ccur);

        while (qd < NQUADS) {
            float4 nAB = make_float4(0.f,0.f,0.f,0.f);
            float4 nCD = make_float4(0.f,0.f,0.f,0.f);
            float  cnx = 0.f;
            int qn = qd + QBLKS*4;
            if (qn < NQUADS) LOAD_QUAD(qn, nAB, nCD, cnx);

            if (ldA || ldB)
                ssacc += ccur * (curAB.x*curAB.x + curAB.y*curAB.y
                               + curAB.z*curAB.z + curAB.w*curAB.w
                               + curCD.x*curCD.x + curCD.y*curCD.y
                               + curCD.z*curCD.z + curCD.w*curCD.w);

            float hA0=b1j, hA1=0.f, hB0=b1j, hB1=0.f;
            float hC0=b1j, hC1=0.f, hD0=b1j, hD1=0.f;
            #pragma unroll
            for (int i = 0; i < 25; ++i) {
                float4 wv = *(const float4*)&w1s[lane*Ee + 4*i];
                hA0 = fmaf(rl(curAB.x, i),    wv.x, hA0);
                hA1 = fmaf(rl(curAB.y, i),    wv.y, hA1);
                hA0 = fmaf(rl(curAB.z, i),    wv.z, hA0);
                hA1 = fmaf(rl(curAB.w, i),    wv.w, hA1);
                hB0 = fmaf(rl(curAB.x, 32+i), wv.x, hB0);
                hB1 = fmaf(rl(curAB.y, 32+i), wv.y, hB1);
                hB0 = fmaf(rl(curAB.z, 32+i), wv.z, hB0);
                hB1 = fmaf(rl(curAB.w, 32+i), wv.w, hB1);
                hC0 = fmaf(rl(curCD.x, i),    wv.x, hC0);
                hC1 = fmaf(rl(curCD.y, i),    wv.y, hC1);
                hC0 = fmaf(rl(curCD.z, i),    wv.z, hC0);
                hC1 = fmaf(rl(curCD.w, i),    wv.w, hC1);
                hD0 = fmaf(rl(curCD.x, 32+i), wv.x, hD0);
                hD1 = fmaf(rl(curCD.y, 32+i), wv.y, hD1);
                hD0 = fmaf(rl(curCD.z, 32+i), wv.z, hD0);
                hD1 = fmaf(rl(curCD.w, 32+i), wv.w, hD1);
            }
            float vA = fmaxf(hA0+hA1, 0.f)*w2j;
            float vB = fmaxf(hB0+hB1, 0.f)*w2j;
            float vC = fmaxf(hC0+hC1, 0.f)*w2j;
            float vD = fmaxf(hD0+hD1, 0.f)*w2j;
            #pragma unroll
            for (int m = 32; m >= 1; m >>= 1) {
                vA += __shfl_xor(vA, m, 64);
                vB += __shfl_xor(vB, m, 64);
                vC += __shfl_xor(vC, m, 64);
                vD += __shfl_xor(vD, m, 64);
            }
            qacc -= 1.f/(1.f+expf(-(vA+b2v))) + 1.f/(1.f+expf(-(vB+b2v)))
                  + 1.f/(1.f+expf(-(vC+b2v))) + 1.f/(1.f+expf(-(vD+b2v)));

            curAB = nAB; curCD = nCD; ccur = cnx; qd = qn;
        }
        #undef LOAD_QUAD

        float s = wave_sum(ssacc);
        if (lane == 0) red[wid] = s + qacc;
        __syncthreads();
        if (tid == 0)
            partialQ[blockIdx.x - PREBLKS] = red[0]+red[1]+red[2]+red[3];
    }
}

// ---------- kernel B: one wave per (b,t); two-phase scan (proven r5/r7 version) ----------
__global__ __launch_bounds__(64) void k_main(
    const float* __restrict__ A, const float* __restrict__ rda0,
    const float* __restrict__ ra0c, const float* __restrict__ kesc,
    const float* __restrict__ kes0, const float* __restrict__ rda0self,
    const int* __restrict__ item_ids, const int* __restrict__ itemset,
    float* __restrict__ partial)
{
    __shared__ float Als[Kk*51];
    __shared__ float Cum[Kk*51];
    __shared__ float2 js[Kk];

    const int bt = blockIdx.x;
    const int b  = bt / Tt;
    const int lane = threadIdx.x;

    for (int i = lane; i < Kk*Kk; i += 64) {
        int k = i / Kk;
        Als[k*51 + (i - k*Kk)] = A[(long)b*Kk*Kk + i];
    }

    const int  myitem = item_ids[bt];
    const bool valid  = lane < Kk;
    const int  cj     = valid ? itemset[b*Kk+lane] : -1;
    const bool mj     = valid && (cj != myitem);
    const unsigned long long mask = __ballot(mj);

    const float rj_own = valid ? rda0[(long)bt*Kk+lane] : 0.f;
    const float kc_own = valid ? kesc[b*Kk+lane] : 0.f;
    const float raj    = valid ? ra0c[(long)bt*Kk+lane] : 0.f;
    if (valid) js[lane] = make_float2(rj_own, kc_own);

    const unsigned mlo = (unsigned)mask, mhi = (unsigned)(mask >> 32);
    const int below = __builtin_amdgcn_mbcnt_hi(mhi, __builtin_amdgcn_mbcnt_lo(mlo, 0));
    const float len    = 1.f + (float)below + (mj ? 1.f : 0.f);
    const float invden = 1.f / ((len + 1.f) * (float)Ee);
    const float invlen = 1.f / ((float)Ee * len);

    float pv = mj ? raj : 0.f;
    #pragma unroll
    for (int off = 1; off <= 32; off <<= 1) {
        float u = __shfl_up(pv, off, 64);
        if (lane >= off) pv += u;
    }
    const float cumra  = pv;
    const float r0self = rda0self[bt];
    const float k0     = kes0[bt];

    asm volatile("s_waitcnt lgkmcnt(0)" ::: "memory");

    if (valid) {
        float cum = 0.f;
        #pragma unroll 5
        for (int k = 0; k < Kk; ++k) {
            float mfk = ((mask >> k) & 1ull) ? 1.0f : 0.0f;
            cum = fmaf(mfk, Als[k*51 + lane], cum);
            Cum[k*51 + lane] = cum;
        }
    }
    asm volatile("s_waitcnt lgkmcnt(0)" ::: "memory");

    const int lc = valid ? lane : (Kk-1);
    float max0 = -3e38f, maxc = -3e38f, diag = 0.f;
    #pragma unroll 2
    for (int j = 0; j < Kk; ++j) {
        float c = Cum[lc*51 + j];
        if (j == lane) diag = c;
        if ((mask >> j) & 1ull) {
            float  a  = Als[lc*51 + j];
            float2 sj = js[j];
            float v0 = fmaf(c + 2.f*sj.x, invden, sj.y);
            float vc = fmaf(a - sj.x,    invden, v0);
            if (lane < j) { max0 = fmaxf(max0, v0); maxc = fmaxf(maxc, vc); }
        }
    }

    float look0 = fmaxf(0.f, max0);
    float lookc = fmaxf(0.f, maxc);
    float Kes0 = k0     + fmaf(r0self + cumra, invlen, look0);
    float KesC = kc_own + fmaf(rj_own + diag,  invlen, lookc);
    float x = Kes0 - KesC;
    float term = (x >= 0.f) ? -log1pf(expf(-x)) : (x - log1pf(expf(x)));
    float contrib = mj ? term : 0.f;
    float s = wave_sum(contrib);
    if (lane == 0) partial[bt] = s;
}

// ---------- kernel C: deterministic final reduce ----------
__global__ __launch_bounds__(256) void k_final(
    const float* __restrict__ p1, int n1,
    const float* __restrict__ p3, int n3,
    float* __restrict__ out)
{
    __shared__ double sh[256];
    double s = 0.0;
    for (int i = threadIdx.x; i < n1; i += 256) s += (double)p1[i];
    for (int i = threadIdx.x; i < n3; i += 256) s += (double)p3[i];
    sh[threadIdx.x] = s;
    __syncthreads();
    for (int m = 128; m >= 1; m >>= 1) {
        if (threadIdx.x < m) sh[threadIdx.x] += sh[threadIdx.x + m];
        __syncthreads();
    }
    if (threadIdx.x == 0) out[0] = (float)sh[0];
}

// ---------- launch ----------
extern "C" void kernel_launch(void* const* d_in, const int* in_sizes, int n_in,
                              void* d_out, int out_size, void* d_ws, size_t ws_size,
                              hipStream_t stream) {
    const float* alpha      = (const float*)d_in[0];
    const float* rho        = (const float*)d_in[1];
    const float* lam        = (const float*)d_in[2];
    const float* beta       = (const float*)d_in[3];
    const float* mu_tab     = (const float*)d_in[4];
    const float* theta      = (const float*)d_in[5];
    const float* gamma_     = (const float*)d_in[6];
    const float* w1         = (const float*)d_in[7];
    const float* b1         = (const float*)d_in[8];
    const float* w2         = (const float*)d_in[9];
    const float* b2         = (const float*)d_in[10];
    const float* sigma_list = (const float*)d_in[11];
    // d_in[12] = mu_list (zeros; folded out)
    const float* prices      = (const float*)d_in[13];
    const float* price_table = (const float*)d_in[14];
    const int*   item_ids    = (const int*)d_in[15];
    const int*   itemset     = (const int*)d_in[16];
    const int*   userid      = (const int*)d_in[17];

    float* ws = (float*)d_ws;
    const size_t offA    = 0;                         // B*K*K
    const size_t offRDA  = offA   + (size_t)Bb*Kk*Kk; // B*T*K
    const size_t offRA0C = offRDA + (size_t)Bb*Tt*Kk; // B*T*K
    const size_t offKESC = offRA0C+ (size_t)Bb*Tt*Kk; // B*K
    const size_t offKES0 = offKESC+ (size_t)Bb*Kk;    // B*T
    const size_t offSELF = offKES0+ (size_t)Bb*Tt;    // B*T
    const size_t offP1   = offSELF+ (size_t)Bb*Tt;    // QBLKS
    const size_t offP3   = offP1  + QBLKS;            // NB3

    k_fused1<<<PREBLKS + QBLKS, 256, 0, stream>>>(
        alpha, rho, lam, beta, mu_tab, theta, gamma_,
        w1, b1, w2, b2, sigma_list, prices, price_table,
        item_ids, itemset, userid,
        ws + offA, ws + offRDA, ws + offRA0C,
        ws + offKESC, ws + offKES0, ws + offSELF,
        ws + offP1);
    k_main<<<NB3, 64, 0, stream>>>(ws + offA, ws + offRDA, ws + offRA0C,
                                   ws + offKESC, ws + offKES0, ws + offSELF,
                                   item_ids, itemset, ws + offP3);
    k_final<<<1, 256, 0, stream>>>(ws + offP1, QBLKS, ws + offP3, NB3, (float*)d_out);
}